// Round 8
// baseline (942.034 us; speedup 1.0000x reference)
//
#include <hip/hip_runtime.h>

#define NN      8000
#define NEXC    6400
#define TSTEPS  200
#define TREF    20
#define NBLK    64
#define TPB     1024
#define NPB     125            // neurons per block: 64 * 125 = 8000
#define EPB     112000         // per-block edge capacity

typedef unsigned int u32x4 __attribute__((ext_vector_type(4)));

// 16B coherent-point (UC) access: sc0 sc1 bypass L1 + non-coherent XCD L2.
__device__ __forceinline__ void store_uc16(unsigned* p, u32x4 v) {
    asm volatile("global_store_dwordx4 %0, %1, off sc0 sc1"
                 :: "v"(p), "v"(v) : "memory");
}
// Two 16B UC loads in flight, single waitcnt -> one-load latency for both.
__device__ __forceinline__ void load_uc16x2(unsigned* pa, unsigned* pb,
                                            u32x4& ra, u32x4& rb) {
    asm volatile("global_load_dwordx4 %0, %2, off sc0 sc1\n\t"
                 "global_load_dwordx4 %1, %3, off sc0 sc1\n\t"
                 "s_waitcnt vmcnt(0)"
                 : "=&v"(ra), "=&v"(rb) : "v"(pa), "v"(pb) : "memory");
}

// -------- row_ptr from sorted pre_idx: row_ptr[i] = lower_bound(pre, i) ------
__global__ void build_rowptr(const int* __restrict__ pre, int nE, int* __restrict__ row_ptr) {
    int i = blockIdx.x * blockDim.x + threadIdx.x;
    if (i > NN) return;
    int lo = 0, hi = nE;
    while (lo < hi) {
        int mid = (lo + hi) >> 1;
        if (pre[mid] < i) lo = mid + 1; else hi = mid;
    }
    row_ptr[i] = lo;
}

// -------- runs[b*NN + p] = first edge of pre p with post >= b*NPB ------------
__global__ void build_runs(const int* __restrict__ post, const int* __restrict__ row_ptr,
                           int* __restrict__ runs) {
    int wid  = (blockIdx.x * blockDim.x + threadIdx.x) >> 6;
    int lane = threadIdx.x & 63;
    int nw   = (gridDim.x * blockDim.x) >> 6;
    for (int p = wid; p < NN; p += nw) {
        int e0 = row_ptr[p], e1 = row_ptr[p + 1];
        int target = lane * NPB;
        int lo = e0, hi = e1;
        while (lo < hi) {
            int mid = (lo + hi) >> 1;
            if (post[mid] < target) lo = mid + 1; else hi = mid;
        }
        runs[lane * NN + p] = lo;
        if (lane == 0) runs[64 * NN + p] = e1;
    }
}

// -------- per-block compacted CSC: brp[b][p] offsets + bedge ushort posts ----
__global__ __launch_bounds__(1024) void build_brp(
    const int* __restrict__ post, const int* __restrict__ runs,
    int* __restrict__ brp, unsigned short* __restrict__ bedge)
{
    __shared__ int wsum[16];
    const int b = blockIdx.x, lt = threadIdx.x;
    const int p0 = lt * 8;                       // 8 pres per thread
    int cnts[8]; int loc = 0;
    for (int j = 0; j < 8; ++j) {
        int p = p0 + j;
        int c = (p < NN) ? (runs[(b + 1) * NN + p] - runs[b * NN + p]) : 0;
        cnts[j] = c; loc += c;
    }
    int x = loc;                                  // wave-inclusive scan
    for (int off = 1; off < 64; off <<= 1) {
        int u = __shfl_up(x, off, 64);
        if ((lt & 63) >= off) x += u;
    }
    if ((lt & 63) == 63) wsum[lt >> 6] = x;
    __syncthreads();
    if (lt < 16) {
        int y = wsum[lt];
        for (int off = 1; off < 16; off <<= 1) {
            int u = __shfl_up(y, off, 16);
            if (lt >= off) y += u;
        }
        wsum[lt] = y;
    }
    __syncthreads();
    int base = x - loc + ((lt >> 6) ? wsum[(lt >> 6) - 1] : 0);
    for (int j = 0; j < 8; ++j) {
        int p = p0 + j;
        if (p < NN) {
            brp[b * (NN + 1) + p] = base;
            int e0 = runs[b * NN + p];
            for (int k = 0; k < cnts[j]; ++k)
                bedge[(size_t)b * EPB + base + k] =
                    (unsigned short)(post[e0 + k] - b * NPB);
            base += cnts[j];
        }
    }
    if (lt == 1023) brp[b * (NN + 1) + NN] = base;
}

__global__ void init_ws(unsigned* chunks) {
    int i = blockIdx.x * blockDim.x + threadIdx.x;
    if (i < 2 * NBLK * 2 * 4) chunks[i] = 0u;
}

// ------------------------------- simulation ----------------------------------
// chunks layout: [parity][block][half] x 16B. Half 0 = neurons 0-63 ballot,
// half 1 = neurons 64-124 ballot; word3 carries the step tag.
__global__ __launch_bounds__(TPB) void sim(
    const float* __restrict__ bg, const float* __restrict__ tau_m,
    const int* __restrict__ brp, const unsigned short* __restrict__ bedge,
    unsigned* __restrict__ chunks, float* __restrict__ out)
{
#pragma clang fp contract(off)
    __shared__ unsigned cnt[NPB];         // packed exc/inh input counts
    __shared__ float    bg_sh[2][NPB];    // double-buffered bg row
    __shared__ int      list_sh[NN];      // global spiker ids this step
    __shared__ int      nspk_sh;

    const int b    = blockIdx.x;
    const int lt   = threadIdx.x;
    const int wave = lt >> 6;
    const int lane = lt & 63;
    const int g    = b * NPB + lt;
    const bool own = (lt < NPB);
    const int* __restrict__ brp_b = brp + b * (NN + 1);
    const unsigned short* __restrict__ bedge_b = bedge + (size_t)b * EPB;

    const float JE = (float)(2.0 * (16.0 / 640.0));        // float32(0.05)
    const float JI = (float)(2.0 * (16.0 / 640.0) * 5.0);  // float32(0.25)
    const float DS = (float)0.98019867330675525;           // exp(-0.1/5)
    const float DA = (float)0.99950012497917929;           // exp(-0.1/200)

    float dv = 0.f, v = 0.f, s = 0.f, a = 0.f, spike = 0.f, sum_v = 0.f;
    int ref = 0, sum_spk = 0;
    if (own) {
        dv = expf(-(0.1f / tau_m[g]));
        cnt[lt] = 0u;
    }
    if (lt >= TPB - 128) {                 // waves 14-15 prefill bg row t=0
        int j = lt - (TPB - 128);
        if (j < NPB) bg_sh[0][j] = bg[b * NPB + j];
    }
    __syncthreads();

    for (int t = 0; t < TSTEPS; ++t) {
        const unsigned tag = ((unsigned)((t + 1) & 7)) << 29;

        // ------------- Phase A (waves 0,1) + immediate per-wave publish ------
        bool ns = false;
        if (own) {
            unsigned c = cnt[lt];
            cnt[lt] = 0u;
            float rec = (float)(c & 0xFFFFu) * JE - (float)(c >> 16) * JI;
            s = s * DS + rec + bg_sh[t & 1][lt];
            a = a * DA + spike;
            bool active = (ref <= 0);
            v = active ? (v * dv + s) : 0.f;
            float thr = 20.0f + 1.6f * a;
            ns = (v >= thr) && active;
            if (ns) v = 0.f;
            ref = ns ? TREF : (ref > 0 ? ref - 1 : 0);
            spike = ns ? 1.f : 0.f;
            sum_spk += ns ? 1 : 0;
            sum_v += v;
        }
        if (wave < 2) {
            unsigned long long bal = __ballot(ns);
            if (lane == 0) {
                u32x4 ch;
                ch[0] = (unsigned)(bal & 0xFFFFFFFFu);
                ch[1] = (unsigned)(bal >> 32);
                ch[2] = 0u;
                ch[3] = tag;
                store_uc16(&chunks[(((t & 1) * NBLK + b) * 2 + wave) * 4], ch);
            }
        }
        // waves 14-15: prefetch next bg row (hidden under poll)
        if (lt >= TPB - 128 && (t + 1) < TSTEPS) {
            int j = lt - (TPB - 128);
            if (j < NPB) bg_sh[(t + 1) & 1][j] = bg[(t + 1) * NN + b * NPB + j];
        }

        // ------------- poll both halves (wave 0), expand -> list -------------
        if (wave == 0) {
            unsigned* pA = &chunks[(((t & 1) * NBLK + lane) * 2 + 0) * 4];
            unsigned* pB = &chunks[(((t & 1) * NBLK + lane) * 2 + 1) * 4];
            u32x4 cA, cB;
            for (;;) {
                load_uc16x2(pA, pB, cA, cB);
                if (cA[3] == tag && cB[3] == tag) break;
            }
            unsigned w0 = cA[0], w1 = cA[1], w2 = cB[0], w3 = cB[1];
            int tot = __popc(w0) + __popc(w1) + __popc(w2) + __popc(w3);
            int x = tot;                           // inclusive wave scan
            for (int off = 1; off < 64; off <<= 1) {
                int u = __shfl_up(x, off, 64);
                if (lane >= off) x += u;
            }
            int pos = x - tot;
            int base = lane * NPB;
            unsigned wd[4] = {w0, w1, w2, w3};
            #pragma unroll
            for (int w = 0; w < 4; ++w) {
                unsigned m = wd[w];
                while (m) {
                    int j = __ffs(m) - 1;
                    m &= m - 1;
                    list_sh[pos++] = base + w * 32 + j;
                }
            }
            if (lane == 63) nspk_sh = x;
        }
        __syncthreads();                           // syncA: list + bg + reset

        // ------------- Phase B: scatter, 2 threads per spike ------------------
        const int ktot = nspk_sh;
        for (int i = lt; i < 2 * ktot; i += TPB) {
            int sp = list_sh[i >> 1];
            int o0 = brp_b[sp];
            int o1 = brp_b[sp + 1];
            int mid = (o0 + o1 + 1) >> 1;
            int s0 = (i & 1) ? mid : o0;
            int s1 = (i & 1) ? o1 : mid;
            unsigned incr = (sp < NEXC) ? 1u : 0x10000u;
            for (int e = s0; e < s1; ++e) {
                atomicAdd(&cnt[bedge_b[e]], incr);
            }
        }
        __syncthreads();                           // syncB: cnt ready for t+1
    }

    if (own) {
        out[g]      = (float)sum_spk / 200.0f;
        out[NN + g] = sum_v / 200.0f;
    }
}

// ------------------------------- launcher ------------------------------------
extern "C" void kernel_launch(void* const* d_in, const int* in_sizes, int n_in,
                              void* d_out, int out_size, void* d_ws, size_t ws_size,
                              hipStream_t stream) {
    const float* bg       = (const float*)d_in[1];
    const float* tau_m    = (const float*)d_in[2];
    const int*   pre_idx  = (const int*)d_in[3];
    const int*   post_idx = (const int*)d_in[4];
    const int    nE       = in_sizes[0];
    float* out = (float*)d_out;

    char* ws = (char*)d_ws;
    size_t off = 0;
    int* runs    = (int*)(ws + off);          off += (size_t)65 * NN * 4;
    int* row_ptr = (int*)(ws + off);          off += (size_t)(NN + 1) * 4;
    off = (off + 63) & ~(size_t)63;
    int* brp     = (int*)(ws + off);          off += (size_t)NBLK * (NN + 1) * 4;
    off = (off + 63) & ~(size_t)63;
    unsigned short* bedge = (unsigned short*)(ws + off); off += (size_t)NBLK * EPB * 2;
    off = (off + 63) & ~(size_t)63;
    unsigned* chunks = (unsigned*)(ws + off); off += (size_t)2 * NBLK * 2 * 16;

    hipLaunchKernelGGL(build_rowptr, dim3(32), dim3(256), 0, stream, pre_idx, nE, row_ptr);
    hipLaunchKernelGGL(build_runs, dim3(256), dim3(256), 0, stream, post_idx, row_ptr, runs);
    hipLaunchKernelGGL(build_brp, dim3(NBLK), dim3(1024), 0, stream, post_idx, runs, brp, bedge);
    hipLaunchKernelGGL(init_ws, dim3(1), dim3(1024), 0, stream, chunks);
    hipLaunchKernelGGL(sim, dim3(NBLK), dim3(TPB), 0, stream,
                       bg, tau_m, brp, bedge, chunks, out);
}